// Round 12
// baseline (4436.026 us; speedup 1.0000x reference)
//
#include <hip/hip_runtime.h>
#include <math.h>

#define NBASES 16
#define HID 64
#define FIL 64
#define TBL 8192
#define DMAX 8.0f
#define TSCALE (8191.0f / 8.0f)
// LDS tile swizzle: row=node, elem j stored at j^node -> uniform-j reads are conflict-free
#define SWZ(nd, j) (((nd) << 6) + ((j) ^ (nd)))

// ShiftedSoftplus: softplus(x) - log(2), overflow-safe form.
__device__ __forceinline__ float sspf(float x) {
    return fmaxf(x, 0.f) + __logf(1.f + __expf(-fabsf(x))) - 0.69314718056f;
}

// ---------------- CSR build: histogram of dst ----------------
__global__ void k_count(const int* __restrict__ ei, int E, int* __restrict__ cnt) {
    int e = blockIdx.x * blockDim.x + threadIdx.x;
    if (e >= E) return;
    atomicAdd(&cnt[ei[E + e]], 1);
}

// ---- 3-phase scan ----
__global__ void k_scan_blk(const int* __restrict__ cnt, int N,
                           int* __restrict__ row_start, int* __restrict__ carry) {
    __shared__ int s[1024];
    int tid = threadIdx.x;
    int idx = blockIdx.x * 1024 + tid;
    int v = (idx < N) ? cnt[idx] : 0;
    s[tid] = v;
    __syncthreads();
    for (int off = 1; off < 1024; off <<= 1) {
        int t = (tid >= off) ? s[tid - off] : 0;
        __syncthreads();
        s[tid] += t;
        __syncthreads();
    }
    if (idx < N) row_start[idx] = s[tid] - v;
    if (tid == 1023) carry[blockIdx.x] = s[1023];
}

__global__ void k_scan_carry(const int* __restrict__ carry, int nblk,
                             int* __restrict__ carry_ex) {
    __shared__ int s[1024];
    int tid = threadIdx.x;
    int v = (tid < nblk) ? carry[tid] : 0;
    s[tid] = v;
    __syncthreads();
    for (int off = 1; off < 1024; off <<= 1) {
        int t = (tid >= off) ? s[tid - off] : 0;
        __syncthreads();
        s[tid] += t;
        __syncthreads();
    }
    if (tid < nblk) carry_ex[tid] = s[tid] - v;
}

__global__ void k_scan_add(int* __restrict__ row_start, const int* __restrict__ carry_ex,
                           int N, int E, int* __restrict__ cursor) {
    int i = blockIdx.x * blockDim.x + threadIdx.x;
    if (i >= N) return;
    int r = row_start[i] + carry_ex[i >> 10];
    row_start[i] = r;
    cursor[i] = r;
    if (i == 0) row_start[N] = E;
}

// fill sorted-edge records: {src, dst, d, C}
__global__ void k_fill(const float* __restrict__ pos, const float* __restrict__ shifts,
                       const int* __restrict__ ei, int E, int* __restrict__ cursor,
                       float4* __restrict__ e_pack) {
    int e = blockIdx.x * blockDim.x + threadIdx.x;
    if (e >= E) return;
    int s = ei[e], t = ei[E + e];
    float dx = pos[t * 3 + 0] - pos[s * 3 + 0] + shifts[e * 3 + 0];
    float dy = pos[t * 3 + 1] - pos[s * 3 + 1] + shifts[e * 3 + 1];
    float dz = pos[t * 3 + 2] - pos[s * 3 + 2] + shifts[e * 3 + 2];
    float d = sqrtf(dx * dx + dy * dy + dz * dz);
    float C = 0.5f * (cosf(d * 0.6283185307179586f) + 1.0f); // pi/CUTOFF = pi/5
    int p = atomicAdd(&cursor[t], 1);
    float4 rec;
    rec.x = __int_as_float(s);
    rec.y = __int_as_float(t);
    rec.z = d;
    rec.w = C;
    e_pack[p] = rec;
}

// ---------------- W(d) lookup tables (fp16): thread = (entry, 4-filter chunk) ----------------
__global__ void __launch_bounds__(256) k_table(
    const float* __restrict__ w1, const float* __restrict__ b1,
    const float* __restrict__ w2, const float* __restrict__ b2,
    _Float16* __restrict__ tab) {
    int i = blockIdx.x * blockDim.x + threadIdx.x;
    if (i >= 2 * TBL * 16) return;
    int chunk = i & 15;
    int ent = i >> 4;
    int l = ent >> 13;
    int ti = ent & (TBL - 1);
    int f0 = chunk * 4;
    const float* w1l = w1 + l * (FIL * NBASES);
    const float* b1l = b1 + l * FIL;
    const float* w2l = w2 + l * (FIL * FIL);
    const float* b2l = b2 + l * FIL;
    float d = (float)ti * (DMAX / (float)(TBL - 1));
    float g[16];
#pragma unroll
    for (int b = 0; b < NBASES; b++) {
        float u = d - (float)b * (5.0f / 15.0f);
        g[b] = __expf(-4.5f * u * u);
    }
    float a0 = b2l[f0 + 0], a1 = b2l[f0 + 1], a2 = b2l[f0 + 2], a3 = b2l[f0 + 3];
#pragma unroll 4
    for (int j = 0; j < FIL; j++) {
        float tt = b1l[j];
#pragma unroll
        for (int b = 0; b < NBASES; b++) tt += w1l[j * NBASES + b] * g[b];
        float hj = sspf(tt);
        a0 += w2l[(f0 + 0) * FIL + j] * hj;
        a1 += w2l[(f0 + 1) * FIL + j] * hj;
        a2 += w2l[(f0 + 2) * FIL + j] * hj;
        a3 += w2l[(f0 + 3) * FIL + j] * hj;
    }
    _Float16* o = tab + (size_t)ent * FIL + f0;
    o[0] = (_Float16)a0; o[1] = (_Float16)a1; o[2] = (_Float16)a2; o[3] = (_Float16)a3;
}

// pack adjacent table rows: tab2[ent][f] = (W_ti[f], W_{ti+1}[f]) as fp16x2 in a uint
__global__ void k_pack(const _Float16* __restrict__ tab, unsigned int* __restrict__ tab2) {
    int i = blockIdx.x * blockDim.x + threadIdx.x;
    if (i >= 2 * TBL * 64) return;
    int ent = i >> 6, f = i & 63;
    int l = ent >> 13, ti = ent & (TBL - 1);
    int tn = ti < TBL - 1 ? ti + 1 : ti;
    union { unsigned int u; _Float16 h[2]; } cv;
    cv.h[0] = tab[((size_t)ent << 6) + f];
    cv.h[1] = tab[((size_t)((l << 13) + tn) << 6) + f];
    tab2[((size_t)ent << 6) + f] = cv.u;
}

// ---- shared helpers for the 64-node-block LDS-staged matvec kernels ----
// stage 64 rows x 64 f32 from global into swizzled LDS tile (coalesced float4 reads)
__device__ __forceinline__ void stage64(const float* __restrict__ src, float* A,
                                        int n0, int N, int tid) {
    const float4* s4 = (const float4*)(src + (size_t)n0 * 64);
#pragma unroll
    for (int q = 0; q < 4; q++) {
        int p = tid + 256 * q;            // float4 index 0..1023
        int nd = p >> 4, jb = (p & 15) << 2;
        if (n0 + nd < N) {
            float4 v = s4[p];
            A[SWZ(nd, jb + 0)] = v.x;
            A[SWZ(nd, jb + 1)] = v.y;
            A[SWZ(nd, jb + 2)] = v.z;
            A[SWZ(nd, jb + 3)] = v.w;
        }
    }
}

// pull own row from swizzled tile into registers (conflict-free: j uniform, node=lane)
__device__ __forceinline__ void loadrow(const float* A, int node, float* av) {
#pragma unroll
    for (int j = 0; j < 64; j++) av[j] = A[SWZ(node, j)];
}

// 16-output matvec chunk; W rows wave-uniform -> s_load; av in VGPRs
__device__ __forceinline__ void mv16(const float* __restrict__ W, const float* __restrict__ b,
                                     int r0, const float* av, float* out) {
#pragma unroll
    for (int k = 0; k < 16; k++) {
        int row = r0 + k;
        const float* w = W + row * 64;
        float acc = b ? b[row] : 0.f;
#pragma unroll
        for (int j = 0; j < 64; j++) acc += w[j] * av[j];
        out[k] = acc;
    }
}

// ---------------- fused embed + layer0 lin1: 64 nodes/block, 4 chunks ----------------
__global__ void __launch_bounds__(256, 2) k_embed_lin1(
    const float* __restrict__ attrs, const float* __restrict__ wv,
    const float* __restrict__ W, int N,
    float* __restrict__ h, _Float16* __restrict__ xfh) {
    __shared__ float A[4096];
    int tid = threadIdx.x;
    int c = tid >> 6, node = tid & 63;
    int n0 = blockIdx.x << 6, n = n0 + node;
    bool act = n < N;
    float a0 = 0.f, a1 = 0.f, a2 = 0.f, a3 = 0.f, a4 = 0.f;
    if (act) {
        a0 = attrs[n * 5 + 0]; a1 = attrs[n * 5 + 1]; a2 = attrs[n * 5 + 2];
        a3 = attrs[n * 5 + 3]; a4 = attrs[n * 5 + 4];
    }
    float t16[16];
#pragma unroll
    for (int k = 0; k < 16; k++) {
        const float* wr = wv + (c * 16 + k) * 5;   // uniform -> s_load
        t16[k] = a0 * wr[0] + a1 * wr[1] + a2 * wr[2] + a3 * wr[3] + a4 * wr[4];
    }
    if (act) {
        float4* hw = (float4*)(h + (size_t)n * 64 + c * 16);
#pragma unroll
        for (int kq = 0; kq < 4; kq++) {
            float4 o; o.x = t16[kq*4]; o.y = t16[kq*4+1]; o.z = t16[kq*4+2]; o.w = t16[kq*4+3];
            hw[kq] = o;
        }
    }
#pragma unroll
    for (int k = 0; k < 16; k++) A[SWZ(node, c * 16 + k)] = t16[k];
    __syncthreads();
    float av[64];
    loadrow(A, node, av);
    mv16(W, nullptr, c * 16, av, t16);
    if (act) {
        union { unsigned int u[8]; _Float16 hh[16]; } pk;
#pragma unroll
        for (int k = 0; k < 16; k++) pk.hh[k] = (_Float16)t16[k];
        unsigned int* o = (unsigned int*)(xfh + (size_t)n * 64 + c * 16);
#pragma unroll
        for (int p = 0; p < 8; p++) o[p] = pk.u[p];
    }
}

// ---------------- fused node update + next lin1: 3 chained matvecs through one LDS tile ----------------
__global__ void __launch_bounds__(256, 2) k_nu_lin1(
    const float* __restrict__ agg,
    const float* __restrict__ lin2w, const float* __restrict__ lin2b,
    const float* __restrict__ linw, const float* __restrict__ linb,
    const float* __restrict__ lin1w_next, int N,
    float* __restrict__ h, _Float16* __restrict__ xfh) {
    __shared__ float A[4096];
    int tid = threadIdx.x;
    int c = tid >> 6, node = tid & 63;
    int n0 = blockIdx.x << 6, n = n0 + node;
    bool act = n < N;
    stage64(agg, A, n0, N, tid);
    __syncthreads();
    float av[64];
    loadrow(A, node, av);
    float t16[16];
    mv16(lin2w, lin2b, c * 16, av, t16);
#pragma unroll
    for (int k = 0; k < 16; k++) t16[k] = sspf(t16[k]);
    __syncthreads();                    // tile fully consumed
#pragma unroll
    for (int k = 0; k < 16; k++) A[SWZ(node, c * 16 + k)] = t16[k];
    __syncthreads();
    loadrow(A, node, av);
    mv16(linw, linb, c * 16, av, t16);
    if (act) {
        float4* hr = (float4*)(h + (size_t)n * 64 + c * 16);
#pragma unroll
        for (int kq = 0; kq < 4; kq++) {
            float4 hh = hr[kq];
            hh.x += t16[kq * 4 + 0]; hh.y += t16[kq * 4 + 1];
            hh.z += t16[kq * 4 + 2]; hh.w += t16[kq * 4 + 3];
            hr[kq] = hh;
            t16[kq * 4 + 0] = hh.x; t16[kq * 4 + 1] = hh.y;
            t16[kq * 4 + 2] = hh.z; t16[kq * 4 + 3] = hh.w;
        }
    }
    __syncthreads();
#pragma unroll
    for (int k = 0; k < 16; k++) A[SWZ(node, c * 16 + k)] = t16[k];
    __syncthreads();
    loadrow(A, node, av);
    mv16(lin1w_next, nullptr, c * 16, av, t16);
    if (act) {
        union { unsigned int u[8]; _Float16 hh[16]; } pk;
#pragma unroll
        for (int k = 0; k < 16; k++) pk.hh[k] = (_Float16)t16[k];
        unsigned int* o = (unsigned int*)(xfh + (size_t)n * 64 + c * 16);
#pragma unroll
        for (int p = 0; p < 8; p++) o[p] = pk.u[p];
    }
}

// ---------------- fused layer-1 node update + readout (h never written) ----------------
__global__ void __launch_bounds__(256, 2) k_nu_ro(
    const float* __restrict__ agg,
    const float* __restrict__ lin2w, const float* __restrict__ lin2b,
    const float* __restrict__ linw, const float* __restrict__ linb,
    const float* __restrict__ h,
    const float* __restrict__ ow1, const float* __restrict__ ob1,
    const float* __restrict__ ow2, const float* __restrict__ ob2, int N,
    float* __restrict__ o_node) {
    __shared__ float A[4096];
    int tid = threadIdx.x;
    int c = tid >> 6, node = tid & 63;
    int n0 = blockIdx.x << 6, n = n0 + node;
    bool act = n < N;
    stage64(agg, A, n0, N, tid);
    __syncthreads();
    float av[64];
    loadrow(A, node, av);
    float t16[16];
    mv16(lin2w, lin2b, c * 16, av, t16);
#pragma unroll
    for (int k = 0; k < 16; k++) t16[k] = sspf(t16[k]);
    __syncthreads();
#pragma unroll
    for (int k = 0; k < 16; k++) A[SWZ(node, c * 16 + k)] = t16[k];
    __syncthreads();
    loadrow(A, node, av);
    mv16(linw, linb, c * 16, av, t16);
    if (act) {
        const float4* hr = (const float4*)(h + (size_t)n * 64 + c * 16);
#pragma unroll
        for (int kq = 0; kq < 4; kq++) {
            float4 hh = hr[kq];
            t16[kq * 4 + 0] += hh.x; t16[kq * 4 + 1] += hh.y;
            t16[kq * 4 + 2] += hh.z; t16[kq * 4 + 3] += hh.w;
        }
    }
    __syncthreads();
#pragma unroll
    for (int k = 0; k < 16; k++) A[SWZ(node, c * 16 + k)] = t16[k];
    __syncthreads();
    loadrow(A, node, av);
    // readout: 8 hidden rows per chunk-thread
    float part = 0.f;
#pragma unroll
    for (int k = 0; k < 8; k++) {
        int row = c * 8 + k;
        const float* w = ow1 + row * 64;           // uniform -> s_load
        float acc = ob1[row];
#pragma unroll
        for (int j = 0; j < 64; j++) acc += w[j] * av[j];
        part += sspf(acc) * ow2[row];
    }
    __syncthreads();                    // tile fully consumed (av in regs)
    A[c * 64 + node] = part;            // linear: lanes=node -> conflict-free
    __syncthreads();
    if (c == 0 && act)
        o_node[n] = A[node] + A[64 + node] + A[128 + node] + A[192 + node] + ob2[0];
}

// ---------------- edge aggregate: wave per node, packed-pair table, 4x unroll ----------------
__global__ void __launch_bounds__(256, 8) k_edge_agg(
    const float4* __restrict__ e_pack, const int* __restrict__ row_start, int N,
    const unsigned int* __restrict__ tab2, const _Float16* __restrict__ xf,
    float* __restrict__ agg) {
    int n = (blockIdx.x * blockDim.x + threadIdx.x) >> 6;
    int lane = threadIdx.x & 63;
    if (n >= N) return;
    int rs = row_start[n], re = row_start[n + 1];
    float acc = 0.f;
    int r = rs;
#define EDGE_TERM(ep) do { \
        int s_ = __float_as_int((ep).x); \
        float x_ = (ep).z * TSCALE; \
        int i0_ = (int)x_; if (i0_ > TBL - 2) i0_ = TBL - 2; \
        float fr_ = fminf(x_ - (float)i0_, 1.0f); \
        union { unsigned int u; _Float16 hh[2]; } cv_; \
        cv_.u = tab2[((size_t)i0_ << 6) + lane]; \
        float t0_ = (float)cv_.hh[0], t1_ = (float)cv_.hh[1]; \
        float xv_ = (float)xf[((size_t)s_ << 6) + lane]; \
        acc += xv_ * (t0_ + (t1_ - t0_) * fr_) * (ep).w; \
    } while (0)
    for (; r + 4 <= re; r += 4) {
        float4 e0 = e_pack[r], e1 = e_pack[r + 1], e2 = e_pack[r + 2], e3 = e_pack[r + 3];
        EDGE_TERM(e0); EDGE_TERM(e1); EDGE_TERM(e2); EDGE_TERM(e3);
    }
    for (; r < re; r++) {
        float4 e0 = e_pack[r];
        EDGE_TERM(e0);
    }
    agg[(size_t)n * 64 + lane] = acc;
#undef EDGE_TERM
}

// ---------------- graph segment boundaries ----------------
__global__ void k_bstart(const int* __restrict__ batch, int N, int G,
                         int* __restrict__ b_start) {
    int g = blockIdx.x * blockDim.x + threadIdx.x;
    if (g > G) return;
    int lo = 0, hi = N;
    while (lo < hi) {
        int mid = (lo + hi) >> 1;
        if (batch[mid] < g) lo = mid + 1;
        else hi = mid;
    }
    b_start[g] = lo;
}

// ---------------- per-graph mean over sorted o_node segments ----------------
__global__ void k_gmean(const float* __restrict__ o_node, const int* __restrict__ b_start,
                        int G, float* __restrict__ out) {
    int g = (blockIdx.x * blockDim.x + threadIdx.x) >> 6;
    int lane = threadIdx.x & 63;
    if (g >= G) return;
    int rs = b_start[g], re = b_start[g + 1];
    float a = 0.f;
    for (int r = rs + lane; r < re; r += 64) a += o_node[r];
#pragma unroll
    for (int m = 1; m < 64; m <<= 1) a += __shfl_xor(a, m, 64);
    if (lane == 0) {
        float cnt = (float)(re - rs);
        out[g] = a / fmaxf(cnt, 1.0f);
    }
}

extern "C" void kernel_launch(void* const* d_in, const int* in_sizes, int n_in,
                              void* d_out, int out_size, void* d_ws, size_t ws_size,
                              hipStream_t stream) {
    const float* pos    = (const float*)d_in[0];
    const float* shifts = (const float*)d_in[1];
    const float* attrs  = (const float*)d_in[2];
    const int*   batch  = (const int*)d_in[3];
    const int*   ei     = (const int*)d_in[4];
    const float* wv     = (const float*)d_in[5];
    const float* mlp_w1 = (const float*)d_in[6];
    const float* mlp_b1 = (const float*)d_in[7];
    const float* mlp_w2 = (const float*)d_in[8];
    const float* mlp_b2 = (const float*)d_in[9];
    const float* lin1w  = (const float*)d_in[10];
    const float* lin2w  = (const float*)d_in[11];
    const float* lin2b  = (const float*)d_in[12];
    const float* linw   = (const float*)d_in[13];
    const float* linb   = (const float*)d_in[14];
    const float* ow1    = (const float*)d_in[15];
    const float* ob1    = (const float*)d_in[16];
    const float* ow2    = (const float*)d_in[17];
    const float* ob2    = (const float*)d_in[18];

    const int N = in_sizes[0] / 3;       // 100000
    const int E = in_sizes[4] / 2;       // 1600000
    const int G = out_size;              // 1000

    char* w = (char*)d_ws;
    size_t off = 0;
    auto alloc = [&](size_t bytes) -> char* {
        char* p = w + off;
        off = (off + bytes + 255) & ~(size_t)255;
        return p;
    };
    int*          cnt       = (int*)alloc((size_t)N * 4);
    int*          row_start = (int*)alloc((size_t)(N + 1) * 4);
    int*          cursor    = (int*)alloc((size_t)N * 4);
    int*          carry     = (int*)alloc(1024 * 4);
    int*          carry_ex  = (int*)alloc(1024 * 4);
    float4*       e_pack    = (float4*)alloc((size_t)E * 16);
    float*        h         = (float*)alloc((size_t)N * HID * 4);
    _Float16*     xfh       = (_Float16*)alloc((size_t)N * FIL * 2);
    float*        agg       = (float*)alloc((size_t)N * FIL * 4);
    _Float16*     tab       = (_Float16*)alloc((size_t)2 * TBL * FIL * 2);
    unsigned int* tab2      = (unsigned int*)alloc((size_t)2 * TBL * FIL * 4);
    float*        o_node    = (float*)alloc((size_t)N * 4);
    int*          b_start   = (int*)alloc((size_t)(G + 1) * 4);
    (void)ws_size;

    const int B = 256;
    const int nblk = (N + 1023) / 1024;
    const int nb64 = (N + 63) / 64;      // 64-node blocks for the LDS-staged kernels

    // CSR build
    hipMemsetAsync(cnt, 0, (size_t)N * 4, stream);
    k_count<<<(E + B - 1) / B, B, 0, stream>>>(ei, E, cnt);
    k_scan_blk<<<nblk, 1024, 0, stream>>>(cnt, N, row_start, carry);
    k_scan_carry<<<1, 1024, 0, stream>>>(carry, nblk, carry_ex);
    k_scan_add<<<(N + B - 1) / B, B, 0, stream>>>(row_start, carry_ex, N, E, cursor);
    k_fill<<<(E + B - 1) / B, B, 0, stream>>>(pos, shifts, ei, E, cursor, e_pack);

    // tables + packing + embed/lin1 + boundaries
    k_table<<<(2 * TBL * 16 + B - 1) / B, B, 0, stream>>>(mlp_w1, mlp_b1, mlp_w2, mlp_b2, tab);
    k_pack<<<(2 * TBL * 64 + B - 1) / B, B, 0, stream>>>(tab, tab2);
    k_embed_lin1<<<nb64, B, 0, stream>>>(attrs, wv, lin1w, N, h, xfh);
    k_bstart<<<(G + 1 + B - 1) / B, B, 0, stream>>>(batch, N, G, b_start);

    const size_t gw = ((size_t)N * 64 + B - 1) / B;
    // layer 0 (node update fused with layer-1 lin1)
    k_edge_agg<<<gw, B, 0, stream>>>(e_pack, row_start, N, tab2, xfh, agg);
    k_nu_lin1<<<nb64, B, 0, stream>>>(agg, lin2w, lin2b, linw, linb,
                                      lin1w + 4096, N, h, xfh);
    // layer 1 (node update fused with readout; h consumed, never rewritten)
    k_edge_agg<<<gw, B, 0, stream>>>(e_pack, row_start, N, tab2 + (size_t)TBL * FIL, xfh, agg);
    k_nu_ro<<<nb64, B, 0, stream>>>(agg, lin2w + 4096, lin2b + 64, linw + 4096, linb + 64,
                                    h, ow1, ob1, ow2, ob2, N, o_node);
    // per-graph mean
    k_gmean<<<((size_t)G * 64 + B - 1) / B, B, 0, stream>>>(o_node, b_start, G, (float*)d_out);
}

// Round 13
// 1306.929 us; speedup vs baseline: 3.3942x; 3.3942x over previous
//
#include <hip/hip_runtime.h>
#include <math.h>

#define NBASES 16
#define HID 64
#define FIL 64
#define TBL 8192
#define DMAX 8.0f
#define TSCALE (8191.0f / 8.0f)
// LDS tile swizzle: row=node, elem j stored at j^node -> uniform-j reads are conflict-free
#define SWZ(nd, j) (((nd) << 6) + ((j) ^ (nd)))

// ShiftedSoftplus: softplus(x) - log(2), overflow-safe form.
__device__ __forceinline__ float sspf(float x) {
    return fmaxf(x, 0.f) + __logf(1.f + __expf(-fabsf(x))) - 0.69314718056f;
}

// ---------------- CSR build: histogram of dst ----------------
__global__ void k_count(const int* __restrict__ ei, int E, int* __restrict__ cnt) {
    int e = blockIdx.x * blockDim.x + threadIdx.x;
    if (e >= E) return;
    atomicAdd(&cnt[ei[E + e]], 1);
}

// ---- 3-phase scan ----
__global__ void k_scan_blk(const int* __restrict__ cnt, int N,
                           int* __restrict__ row_start, int* __restrict__ carry) {
    __shared__ int s[1024];
    int tid = threadIdx.x;
    int idx = blockIdx.x * 1024 + tid;
    int v = (idx < N) ? cnt[idx] : 0;
    s[tid] = v;
    __syncthreads();
    for (int off = 1; off < 1024; off <<= 1) {
        int t = (tid >= off) ? s[tid - off] : 0;
        __syncthreads();
        s[tid] += t;
        __syncthreads();
    }
    if (idx < N) row_start[idx] = s[tid] - v;
    if (tid == 1023) carry[blockIdx.x] = s[1023];
}

__global__ void k_scan_carry(const int* __restrict__ carry, int nblk,
                             int* __restrict__ carry_ex) {
    __shared__ int s[1024];
    int tid = threadIdx.x;
    int v = (tid < nblk) ? carry[tid] : 0;
    s[tid] = v;
    __syncthreads();
    for (int off = 1; off < 1024; off <<= 1) {
        int t = (tid >= off) ? s[tid - off] : 0;
        __syncthreads();
        s[tid] += t;
        __syncthreads();
    }
    if (tid < nblk) carry_ex[tid] = s[tid] - v;
}

__global__ void k_scan_add(int* __restrict__ row_start, const int* __restrict__ carry_ex,
                           int N, int E, int* __restrict__ cursor) {
    int i = blockIdx.x * blockDim.x + threadIdx.x;
    if (i >= N) return;
    int r = row_start[i] + carry_ex[i >> 10];
    row_start[i] = r;
    cursor[i] = r;
    if (i == 0) row_start[N] = E;
}

// fill sorted-edge records: {src, dst, d, C}
__global__ void k_fill(const float* __restrict__ pos, const float* __restrict__ shifts,
                       const int* __restrict__ ei, int E, int* __restrict__ cursor,
                       float4* __restrict__ e_pack) {
    int e = blockIdx.x * blockDim.x + threadIdx.x;
    if (e >= E) return;
    int s = ei[e], t = ei[E + e];
    float dx = pos[t * 3 + 0] - pos[s * 3 + 0] + shifts[e * 3 + 0];
    float dy = pos[t * 3 + 1] - pos[s * 3 + 1] + shifts[e * 3 + 1];
    float dz = pos[t * 3 + 2] - pos[s * 3 + 2] + shifts[e * 3 + 2];
    float d = sqrtf(dx * dx + dy * dy + dz * dz);
    float C = 0.5f * (cosf(d * 0.6283185307179586f) + 1.0f); // pi/CUTOFF = pi/5
    int p = atomicAdd(&cursor[t], 1);
    float4 rec;
    rec.x = __int_as_float(s);
    rec.y = __int_as_float(t);
    rec.z = d;
    rec.w = C;
    e_pack[p] = rec;
}

// ---------------- W(d) lookup tables (fp16): thread = (entry, 4-filter chunk) ----------------
__global__ void __launch_bounds__(256) k_table(
    const float* __restrict__ w1, const float* __restrict__ b1,
    const float* __restrict__ w2, const float* __restrict__ b2,
    _Float16* __restrict__ tab) {
    int i = blockIdx.x * blockDim.x + threadIdx.x;
    if (i >= 2 * TBL * 16) return;
    int chunk = i & 15;
    int ent = i >> 4;
    int l = ent >> 13;
    int ti = ent & (TBL - 1);
    int f0 = chunk * 4;
    const float* w1l = w1 + l * (FIL * NBASES);
    const float* b1l = b1 + l * FIL;
    const float* w2l = w2 + l * (FIL * FIL);
    const float* b2l = b2 + l * FIL;
    float d = (float)ti * (DMAX / (float)(TBL - 1));
    float g[16];
#pragma unroll
    for (int b = 0; b < NBASES; b++) {
        float u = d - (float)b * (5.0f / 15.0f);
        g[b] = __expf(-4.5f * u * u);
    }
    float a0 = b2l[f0 + 0], a1 = b2l[f0 + 1], a2 = b2l[f0 + 2], a3 = b2l[f0 + 3];
#pragma unroll 4
    for (int j = 0; j < FIL; j++) {
        float tt = b1l[j];
#pragma unroll
        for (int b = 0; b < NBASES; b++) tt += w1l[j * NBASES + b] * g[b];
        float hj = sspf(tt);
        a0 += w2l[(f0 + 0) * FIL + j] * hj;
        a1 += w2l[(f0 + 1) * FIL + j] * hj;
        a2 += w2l[(f0 + 2) * FIL + j] * hj;
        a3 += w2l[(f0 + 3) * FIL + j] * hj;
    }
    _Float16* o = tab + (size_t)ent * FIL + f0;
    o[0] = (_Float16)a0; o[1] = (_Float16)a1; o[2] = (_Float16)a2; o[3] = (_Float16)a3;
}

// pack adjacent table rows: tab2[ent][f] = (W_ti[f], W_{ti+1}[f]) as fp16x2 in a uint
__global__ void k_pack(const _Float16* __restrict__ tab, unsigned int* __restrict__ tab2) {
    int i = blockIdx.x * blockDim.x + threadIdx.x;
    if (i >= 2 * TBL * 64) return;
    int ent = i >> 6, f = i & 63;
    int l = ent >> 13, ti = ent & (TBL - 1);
    int tn = ti < TBL - 1 ? ti + 1 : ti;
    union { unsigned int u; _Float16 h[2]; } cv;
    cv.h[0] = tab[((size_t)ent << 6) + f];
    cv.h[1] = tab[((size_t)((l << 13) + tn) << 6) + f];
    tab2[((size_t)ent << 6) + f] = cv.u;
}

// ---- shared helpers for the 64-node-block LDS-staged matvec kernels ----
// stage 64 rows x 64 f32 from global into swizzled LDS tile (coalesced float4 reads)
__device__ __forceinline__ void stage64(const float* __restrict__ src, float* A,
                                        int n0, int N, int tid) {
    const float4* s4 = (const float4*)(src + (size_t)n0 * 64);
#pragma unroll
    for (int q = 0; q < 4; q++) {
        int p = tid + 256 * q;            // float4 index 0..1023
        int nd = p >> 4, jb = (p & 15) << 2;
        if (n0 + nd < N) {
            float4 v = s4[p];
            A[SWZ(nd, jb + 0)] = v.x;
            A[SWZ(nd, jb + 1)] = v.y;
            A[SWZ(nd, jb + 2)] = v.z;
            A[SWZ(nd, jb + 3)] = v.w;
        }
    }
}

// 16-output matvec chunk reading the input row DIRECTLY from LDS inside the FMA loop
// (no av[64] register copy -- round-12's 128-VGPR spill fix). node==lane, j uniform
// -> A[SWZ(node,j)] is one conflict-free ds_read_b32 per j (2 lanes/bank).
// W rows wave-uniform -> s_load. Live regs: out[16] + aj + temps ~= 40.
__device__ __forceinline__ void mv16_lds(const float* __restrict__ W, const float* __restrict__ b,
                                         int r0, const float* __restrict__ A, int node,
                                         float* out) {
#pragma unroll
    for (int k = 0; k < 16; k++) out[k] = b ? b[r0 + k] : 0.f;
#pragma unroll
    for (int j = 0; j < 64; j++) {
        float aj = A[SWZ(node, j)];
#pragma unroll
        for (int k = 0; k < 16; k++) out[k] += W[(r0 + k) * 64 + j] * aj;
    }
}

// ---------------- fused embed + layer0 lin1: 64 nodes/block, 4 chunks ----------------
__global__ void __launch_bounds__(256, 4) k_embed_lin1(
    const float* __restrict__ attrs, const float* __restrict__ wv,
    const float* __restrict__ W, int N,
    float* __restrict__ h, _Float16* __restrict__ xfh) {
    __shared__ float A[4096];
    int tid = threadIdx.x;
    int c = tid >> 6, node = tid & 63;
    int n0 = blockIdx.x << 6, n = n0 + node;
    bool act = n < N;
    float a0 = 0.f, a1 = 0.f, a2 = 0.f, a3 = 0.f, a4 = 0.f;
    if (act) {
        a0 = attrs[n * 5 + 0]; a1 = attrs[n * 5 + 1]; a2 = attrs[n * 5 + 2];
        a3 = attrs[n * 5 + 3]; a4 = attrs[n * 5 + 4];
    }
    float t16[16];
#pragma unroll
    for (int k = 0; k < 16; k++) {
        const float* wr = wv + (c * 16 + k) * 5;   // uniform -> s_load
        t16[k] = a0 * wr[0] + a1 * wr[1] + a2 * wr[2] + a3 * wr[3] + a4 * wr[4];
    }
    if (act) {
        float4* hw = (float4*)(h + (size_t)n * 64 + c * 16);
#pragma unroll
        for (int kq = 0; kq < 4; kq++) {
            float4 o; o.x = t16[kq*4]; o.y = t16[kq*4+1]; o.z = t16[kq*4+2]; o.w = t16[kq*4+3];
            hw[kq] = o;
        }
    }
#pragma unroll
    for (int k = 0; k < 16; k++) A[SWZ(node, c * 16 + k)] = t16[k];
    __syncthreads();
    mv16_lds(W, nullptr, c * 16, A, node, t16);
    if (act) {
        union { unsigned int u[8]; _Float16 hh[16]; } pk;
#pragma unroll
        for (int k = 0; k < 16; k++) pk.hh[k] = (_Float16)t16[k];
        unsigned int* o = (unsigned int*)(xfh + (size_t)n * 64 + c * 16);
#pragma unroll
        for (int p = 0; p < 8; p++) o[p] = pk.u[p];
    }
}

// ---------------- fused node update + next lin1: 3 chained matvecs through one LDS tile ----------------
__global__ void __launch_bounds__(256, 4) k_nu_lin1(
    const float* __restrict__ agg,
    const float* __restrict__ lin2w, const float* __restrict__ lin2b,
    const float* __restrict__ linw, const float* __restrict__ linb,
    const float* __restrict__ lin1w_next, int N,
    float* __restrict__ h, _Float16* __restrict__ xfh) {
    __shared__ float A[4096];
    int tid = threadIdx.x;
    int c = tid >> 6, node = tid & 63;
    int n0 = blockIdx.x << 6, n = n0 + node;
    bool act = n < N;
    stage64(agg, A, n0, N, tid);
    __syncthreads();
    float t16[16];
    mv16_lds(lin2w, lin2b, c * 16, A, node, t16);
#pragma unroll
    for (int k = 0; k < 16; k++) t16[k] = sspf(t16[k]);
    __syncthreads();                    // tile fully consumed
#pragma unroll
    for (int k = 0; k < 16; k++) A[SWZ(node, c * 16 + k)] = t16[k];
    __syncthreads();
    mv16_lds(linw, linb, c * 16, A, node, t16);
    if (act) {
        float4* hr = (float4*)(h + (size_t)n * 64 + c * 16);
#pragma unroll
        for (int kq = 0; kq < 4; kq++) {
            float4 hh = hr[kq];
            hh.x += t16[kq * 4 + 0]; hh.y += t16[kq * 4 + 1];
            hh.z += t16[kq * 4 + 2]; hh.w += t16[kq * 4 + 3];
            hr[kq] = hh;
            t16[kq * 4 + 0] = hh.x; t16[kq * 4 + 1] = hh.y;
            t16[kq * 4 + 2] = hh.z; t16[kq * 4 + 3] = hh.w;
        }
    }
    __syncthreads();
#pragma unroll
    for (int k = 0; k < 16; k++) A[SWZ(node, c * 16 + k)] = t16[k];
    __syncthreads();
    mv16_lds(lin1w_next, nullptr, c * 16, A, node, t16);
    if (act) {
        union { unsigned int u[8]; _Float16 hh[16]; } pk;
#pragma unroll
        for (int k = 0; k < 16; k++) pk.hh[k] = (_Float16)t16[k];
        unsigned int* o = (unsigned int*)(xfh + (size_t)n * 64 + c * 16);
#pragma unroll
        for (int p = 0; p < 8; p++) o[p] = pk.u[p];
    }
}

// ---------------- fused layer-1 node update + readout (h never written) ----------------
__global__ void __launch_bounds__(256, 4) k_nu_ro(
    const float* __restrict__ agg,
    const float* __restrict__ lin2w, const float* __restrict__ lin2b,
    const float* __restrict__ linw, const float* __restrict__ linb,
    const float* __restrict__ h,
    const float* __restrict__ ow1, const float* __restrict__ ob1,
    const float* __restrict__ ow2, const float* __restrict__ ob2, int N,
    float* __restrict__ o_node) {
    __shared__ float A[4096];
    int tid = threadIdx.x;
    int c = tid >> 6, node = tid & 63;
    int n0 = blockIdx.x << 6, n = n0 + node;
    bool act = n < N;
    stage64(agg, A, n0, N, tid);
    __syncthreads();
    float t16[16];
    mv16_lds(lin2w, lin2b, c * 16, A, node, t16);
#pragma unroll
    for (int k = 0; k < 16; k++) t16[k] = sspf(t16[k]);
    __syncthreads();
#pragma unroll
    for (int k = 0; k < 16; k++) A[SWZ(node, c * 16 + k)] = t16[k];
    __syncthreads();
    mv16_lds(linw, linb, c * 16, A, node, t16);
    if (act) {
        const float4* hr = (const float4*)(h + (size_t)n * 64 + c * 16);
#pragma unroll
        for (int kq = 0; kq < 4; kq++) {
            float4 hh = hr[kq];
            t16[kq * 4 + 0] += hh.x; t16[kq * 4 + 1] += hh.y;
            t16[kq * 4 + 2] += hh.z; t16[kq * 4 + 3] += hh.w;
        }
    }
    __syncthreads();
#pragma unroll
    for (int k = 0; k < 16; k++) A[SWZ(node, c * 16 + k)] = t16[k];
    __syncthreads();
    // readout: 8 hidden rows per chunk-thread, reading h-row directly from LDS
    float part = 0.f;
    {
        float acc8[8];
#pragma unroll
        for (int k = 0; k < 8; k++) acc8[k] = ob1[c * 8 + k];
#pragma unroll
        for (int j = 0; j < 64; j++) {
            float aj = A[SWZ(node, j)];
#pragma unroll
            for (int k = 0; k < 8; k++) acc8[k] += ow1[(c * 8 + k) * 64 + j] * aj;
        }
#pragma unroll
        for (int k = 0; k < 8; k++) part += sspf(acc8[k]) * ow2[c * 8 + k];
    }
    __syncthreads();                    // tile fully consumed
    A[c * 64 + node] = part;            // linear: lanes=node -> conflict-free
    __syncthreads();
    if (c == 0 && act)
        o_node[n] = A[node] + A[64 + node] + A[128 + node] + A[192 + node] + ob2[0];
}

// ---------------- edge aggregate: wave per node, packed-pair table, 4x unroll ----------------
__global__ void __launch_bounds__(256, 8) k_edge_agg(
    const float4* __restrict__ e_pack, const int* __restrict__ row_start, int N,
    const unsigned int* __restrict__ tab2, const _Float16* __restrict__ xf,
    float* __restrict__ agg) {
    int n = (blockIdx.x * blockDim.x + threadIdx.x) >> 6;
    int lane = threadIdx.x & 63;
    if (n >= N) return;
    int rs = row_start[n], re = row_start[n + 1];
    float acc = 0.f;
    int r = rs;
#define EDGE_TERM(ep) do { \
        int s_ = __float_as_int((ep).x); \
        float x_ = (ep).z * TSCALE; \
        int i0_ = (int)x_; if (i0_ > TBL - 2) i0_ = TBL - 2; \
        float fr_ = fminf(x_ - (float)i0_, 1.0f); \
        union { unsigned int u; _Float16 hh[2]; } cv_; \
        cv_.u = tab2[((size_t)i0_ << 6) + lane]; \
        float t0_ = (float)cv_.hh[0], t1_ = (float)cv_.hh[1]; \
        float xv_ = (float)xf[((size_t)s_ << 6) + lane]; \
        acc += xv_ * (t0_ + (t1_ - t0_) * fr_) * (ep).w; \
    } while (0)
    for (; r + 4 <= re; r += 4) {
        float4 e0 = e_pack[r], e1 = e_pack[r + 1], e2 = e_pack[r + 2], e3 = e_pack[r + 3];
        EDGE_TERM(e0); EDGE_TERM(e1); EDGE_TERM(e2); EDGE_TERM(e3);
    }
    for (; r < re; r++) {
        float4 e0 = e_pack[r];
        EDGE_TERM(e0);
    }
    agg[(size_t)n * 64 + lane] = acc;
#undef EDGE_TERM
}

// ---------------- graph segment boundaries ----------------
__global__ void k_bstart(const int* __restrict__ batch, int N, int G,
                         int* __restrict__ b_start) {
    int g = blockIdx.x * blockDim.x + threadIdx.x;
    if (g > G) return;
    int lo = 0, hi = N;
    while (lo < hi) {
        int mid = (lo + hi) >> 1;
        if (batch[mid] < g) lo = mid + 1;
        else hi = mid;
    }
    b_start[g] = lo;
}

// ---------------- per-graph mean over sorted o_node segments ----------------
__global__ void k_gmean(const float* __restrict__ o_node, const int* __restrict__ b_start,
                        int G, float* __restrict__ out) {
    int g = (blockIdx.x * blockDim.x + threadIdx.x) >> 6;
    int lane = threadIdx.x & 63;
    if (g >= G) return;
    int rs = b_start[g], re = b_start[g + 1];
    float a = 0.f;
    for (int r = rs + lane; r < re; r += 64) a += o_node[r];
#pragma unroll
    for (int m = 1; m < 64; m <<= 1) a += __shfl_xor(a, m, 64);
    if (lane == 0) {
        float cnt = (float)(re - rs);
        out[g] = a / fmaxf(cnt, 1.0f);
    }
}

extern "C" void kernel_launch(void* const* d_in, const int* in_sizes, int n_in,
                              void* d_out, int out_size, void* d_ws, size_t ws_size,
                              hipStream_t stream) {
    const float* pos    = (const float*)d_in[0];
    const float* shifts = (const float*)d_in[1];
    const float* attrs  = (const float*)d_in[2];
    const int*   batch  = (const int*)d_in[3];
    const int*   ei     = (const int*)d_in[4];
    const float* wv     = (const float*)d_in[5];
    const float* mlp_w1 = (const float*)d_in[6];
    const float* mlp_b1 = (const float*)d_in[7];
    const float* mlp_w2 = (const float*)d_in[8];
    const float* mlp_b2 = (const float*)d_in[9];
    const float* lin1w  = (const float*)d_in[10];
    const float* lin2w  = (const float*)d_in[11];
    const float* lin2b  = (const float*)d_in[12];
    const float* linw   = (const float*)d_in[13];
    const float* linb   = (const float*)d_in[14];
    const float* ow1    = (const float*)d_in[15];
    const float* ob1    = (const float*)d_in[16];
    const float* ow2    = (const float*)d_in[17];
    const float* ob2    = (const float*)d_in[18];

    const int N = in_sizes[0] / 3;       // 100000
    const int E = in_sizes[4] / 2;       // 1600000
    const int G = out_size;              // 1000

    char* w = (char*)d_ws;
    size_t off = 0;
    auto alloc = [&](size_t bytes) -> char* {
        char* p = w + off;
        off = (off + bytes + 255) & ~(size_t)255;
        return p;
    };
    int*          cnt       = (int*)alloc((size_t)N * 4);
    int*          row_start = (int*)alloc((size_t)(N + 1) * 4);
    int*          cursor    = (int*)alloc((size_t)N * 4);
    int*          carry     = (int*)alloc(1024 * 4);
    int*          carry_ex  = (int*)alloc(1024 * 4);
    float4*       e_pack    = (float4*)alloc((size_t)E * 16);
    float*        h         = (float*)alloc((size_t)N * HID * 4);
    _Float16*     xfh       = (_Float16*)alloc((size_t)N * FIL * 2);
    float*        agg       = (float*)alloc((size_t)N * FIL * 4);
    _Float16*     tab       = (_Float16*)alloc((size_t)2 * TBL * FIL * 2);
    unsigned int* tab2      = (unsigned int*)alloc((size_t)2 * TBL * FIL * 4);
    float*        o_node    = (float*)alloc((size_t)N * 4);
    int*          b_start   = (int*)alloc((size_t)(G + 1) * 4);
    (void)ws_size;

    const int B = 256;
    const int nblk = (N + 1023) / 1024;
    const int nb64 = (N + 63) / 64;      // 64-node blocks for the LDS-staged kernels

    // CSR build
    hipMemsetAsync(cnt, 0, (size_t)N * 4, stream);
    k_count<<<(E + B - 1) / B, B, 0, stream>>>(ei, E, cnt);
    k_scan_blk<<<nblk, 1024, 0, stream>>>(cnt, N, row_start, carry);
    k_scan_carry<<<1, 1024, 0, stream>>>(carry, nblk, carry_ex);
    k_scan_add<<<(N + B - 1) / B, B, 0, stream>>>(row_start, carry_ex, N, E, cursor);
    k_fill<<<(E + B - 1) / B, B, 0, stream>>>(pos, shifts, ei, E, cursor, e_pack);

    // tables + packing + embed/lin1 + boundaries
    k_table<<<(2 * TBL * 16 + B - 1) / B, B, 0, stream>>>(mlp_w1, mlp_b1, mlp_w2, mlp_b2, tab);
    k_pack<<<(2 * TBL * 64 + B - 1) / B, B, 0, stream>>>(tab, tab2);
    k_embed_lin1<<<nb64, B, 0, stream>>>(attrs, wv, lin1w, N, h, xfh);
    k_bstart<<<(G + 1 + B - 1) / B, B, 0, stream>>>(batch, N, G, b_start);

    const size_t gw = ((size_t)N * 64 + B - 1) / B;
    // layer 0 (node update fused with layer-1 lin1)
    k_edge_agg<<<gw, B, 0, stream>>>(e_pack, row_start, N, tab2, xfh, agg);
    k_nu_lin1<<<nb64, B, 0, stream>>>(agg, lin2w, lin2b, linw, linb,
                                      lin1w + 4096, N, h, xfh);
    // layer 1 (node update fused with readout; h consumed, never rewritten)
    k_edge_agg<<<gw, B, 0, stream>>>(e_pack, row_start, N, tab2 + (size_t)TBL * FIL, xfh, agg);
    k_nu_ro<<<nb64, B, 0, stream>>>(agg, lin2w + 4096, lin2b + 64, linw + 4096, linb + 64,
                                    h, ow1, ob1, ow2, ob2, N, o_node);
    // per-graph mean
    k_gmean<<<((size_t)G * 64 + B - 1) / B, B, 0, stream>>>(o_node, b_start, G, (float*)d_out);
}

// Round 14
// 944.869 us; speedup vs baseline: 4.6949x; 1.3832x over previous
//
#include <hip/hip_runtime.h>
#include <math.h>

#define NBASES 16
#define HID 64
#define FIL 64
#define TBL 8192
#define DMAX 8.0f
#define TSCALE (8191.0f / 8.0f)
// LDS tile swizzle: row=node, elem j stored at j^node -> uniform-j reads are conflict-free
#define SWZ(nd, j) (((nd) << 6) + ((j) ^ (nd)))

// ShiftedSoftplus: softplus(x) - log(2), overflow-safe form.
__device__ __forceinline__ float sspf(float x) {
    return fmaxf(x, 0.f) + __logf(1.f + __expf(-fabsf(x))) - 0.69314718056f;
}

// ---------------- CSR build: histogram of dst ----------------
__global__ void k_count(const int* __restrict__ ei, int E, int* __restrict__ cnt) {
    int e = blockIdx.x * blockDim.x + threadIdx.x;
    if (e >= E) return;
    atomicAdd(&cnt[ei[E + e]], 1);
}

// ---- 3-phase scan ----
__global__ void k_scan_blk(const int* __restrict__ cnt, int N,
                           int* __restrict__ row_start, int* __restrict__ carry) {
    __shared__ int s[1024];
    int tid = threadIdx.x;
    int idx = blockIdx.x * 1024 + tid;
    int v = (idx < N) ? cnt[idx] : 0;
    s[tid] = v;
    __syncthreads();
    for (int off = 1; off < 1024; off <<= 1) {
        int t = (tid >= off) ? s[tid - off] : 0;
        __syncthreads();
        s[tid] += t;
        __syncthreads();
    }
    if (idx < N) row_start[idx] = s[tid] - v;
    if (tid == 1023) carry[blockIdx.x] = s[1023];
}

__global__ void k_scan_carry(const int* __restrict__ carry, int nblk,
                             int* __restrict__ carry_ex) {
    __shared__ int s[1024];
    int tid = threadIdx.x;
    int v = (tid < nblk) ? carry[tid] : 0;
    s[tid] = v;
    __syncthreads();
    for (int off = 1; off < 1024; off <<= 1) {
        int t = (tid >= off) ? s[tid - off] : 0;
        __syncthreads();
        s[tid] += t;
        __syncthreads();
    }
    if (tid < nblk) carry_ex[tid] = s[tid] - v;
}

__global__ void k_scan_add(int* __restrict__ row_start, const int* __restrict__ carry_ex,
                           int N, int E, int* __restrict__ cursor) {
    int i = blockIdx.x * blockDim.x + threadIdx.x;
    if (i >= N) return;
    int r = row_start[i] + carry_ex[i >> 10];
    row_start[i] = r;
    cursor[i] = r;
    if (i == 0) row_start[N] = E;
}

// fill sorted-edge records: {src, dst, d, C}
__global__ void k_fill(const float* __restrict__ pos, const float* __restrict__ shifts,
                       const int* __restrict__ ei, int E, int* __restrict__ cursor,
                       float4* __restrict__ e_pack) {
    int e = blockIdx.x * blockDim.x + threadIdx.x;
    if (e >= E) return;
    int s = ei[e], t = ei[E + e];
    float dx = pos[t * 3 + 0] - pos[s * 3 + 0] + shifts[e * 3 + 0];
    float dy = pos[t * 3 + 1] - pos[s * 3 + 1] + shifts[e * 3 + 1];
    float dz = pos[t * 3 + 2] - pos[s * 3 + 2] + shifts[e * 3 + 2];
    float d = sqrtf(dx * dx + dy * dy + dz * dz);
    float C = 0.5f * (cosf(d * 0.6283185307179586f) + 1.0f); // pi/CUTOFF = pi/5
    int p = atomicAdd(&cursor[t], 1);
    float4 rec;
    rec.x = __int_as_float(s);
    rec.y = __int_as_float(t);
    rec.z = d;
    rec.w = C;
    e_pack[p] = rec;
}

// ---------------- W(d) lookup tables (fp16): thread = (entry, 4-filter chunk) ----------------
__global__ void __launch_bounds__(256) k_table(
    const float* __restrict__ w1, const float* __restrict__ b1,
    const float* __restrict__ w2, const float* __restrict__ b2,
    _Float16* __restrict__ tab) {
    int i = blockIdx.x * blockDim.x + threadIdx.x;
    if (i >= 2 * TBL * 16) return;
    int chunk = i & 15;
    int ent = i >> 4;
    int l = ent >> 13;
    int ti = ent & (TBL - 1);
    int f0 = chunk * 4;
    const float* w1l = w1 + l * (FIL * NBASES);
    const float* b1l = b1 + l * FIL;
    const float* w2l = w2 + l * (FIL * FIL);
    const float* b2l = b2 + l * FIL;
    float d = (float)ti * (DMAX / (float)(TBL - 1));
    float g[16];
#pragma unroll
    for (int b = 0; b < NBASES; b++) {
        float u = d - (float)b * (5.0f / 15.0f);
        g[b] = __expf(-4.5f * u * u);
    }
    float a0 = b2l[f0 + 0], a1 = b2l[f0 + 1], a2 = b2l[f0 + 2], a3 = b2l[f0 + 3];
#pragma unroll 4
    for (int j = 0; j < FIL; j++) {
        float tt = b1l[j];
#pragma unroll
        for (int b = 0; b < NBASES; b++) tt += w1l[j * NBASES + b] * g[b];
        float hj = sspf(tt);
        a0 += w2l[(f0 + 0) * FIL + j] * hj;
        a1 += w2l[(f0 + 1) * FIL + j] * hj;
        a2 += w2l[(f0 + 2) * FIL + j] * hj;
        a3 += w2l[(f0 + 3) * FIL + j] * hj;
    }
    _Float16* o = tab + (size_t)ent * FIL + f0;
    o[0] = (_Float16)a0; o[1] = (_Float16)a1; o[2] = (_Float16)a2; o[3] = (_Float16)a3;
}

// pack adjacent table rows: tab2[ent][f] = (W_ti[f], W_{ti+1}[f]) as fp16x2 in a uint
__global__ void k_pack(const _Float16* __restrict__ tab, unsigned int* __restrict__ tab2) {
    int i = blockIdx.x * blockDim.x + threadIdx.x;
    if (i >= 2 * TBL * 64) return;
    int ent = i >> 6, f = i & 63;
    int l = ent >> 13, ti = ent & (TBL - 1);
    int tn = ti < TBL - 1 ? ti + 1 : ti;
    union { unsigned int u; _Float16 h[2]; } cv;
    cv.h[0] = tab[((size_t)ent << 6) + f];
    cv.h[1] = tab[((size_t)((l << 13) + tn) << 6) + f];
    tab2[((size_t)ent << 6) + f] = cv.u;
}

// ---- shared helpers for the 64-node-block LDS-staged matvec kernels ----
// stage 64 rows x 64 f32 from global into swizzled LDS tile (coalesced float4 reads)
__device__ __forceinline__ void stage64(const float* __restrict__ src, float* A,
                                        int n0, int N, int tid) {
    const float4* s4 = (const float4*)(src + (size_t)n0 * 64);
#pragma unroll
    for (int q = 0; q < 4; q++) {
        int p = tid + 256 * q;            // float4 index 0..1023
        int nd = p >> 4, jb = (p & 15) << 2;
        if (n0 + nd < N) {
            float4 v = s4[p];
            A[SWZ(nd, jb + 0)] = v.x;
            A[SWZ(nd, jb + 1)] = v.y;
            A[SWZ(nd, jb + 2)] = v.z;
            A[SWZ(nd, jb + 3)] = v.w;
        }
    }
}

// 16-output matvec chunk reading the input row DIRECTLY from LDS inside the FMA loop.
// r0 MUST be SGPR-resident (pass readfirstlane'd chunk) so W addresses scalarize to
// s_load (round-13: c=tid>>6 not provably uniform -> VGPR addressing -> spill -> 700MB
// scratch traffic). node==lane, j uniform -> A[SWZ(node,j)] conflict-free (2 lanes/bank).
__device__ __forceinline__ void mv16_lds(const float* __restrict__ W, const float* __restrict__ b,
                                         int r0, const float* __restrict__ A, int node,
                                         float* out) {
#pragma unroll
    for (int k = 0; k < 16; k++) out[k] = b ? b[r0 + k] : 0.f;
#pragma unroll
    for (int j = 0; j < 64; j++) {
        float aj = A[SWZ(node, j)];
#pragma unroll
        for (int k = 0; k < 16; k++) out[k] += W[(r0 + k) * 64 + j] * aj;
    }
}

// ---------------- fused embed + layer0 lin1: 64 nodes/block, 4 chunks ----------------
__global__ void __launch_bounds__(256, 4) k_embed_lin1(
    const float* __restrict__ attrs, const float* __restrict__ wv,
    const float* __restrict__ W, int N,
    float* __restrict__ h, _Float16* __restrict__ xfh) {
    __shared__ float A[4096];
    int tid = threadIdx.x;
    int c = __builtin_amdgcn_readfirstlane(tid >> 6);  // SGPR chunk idx -> s_load weights
    int node = tid & 63;
    int n0 = blockIdx.x << 6, n = n0 + node;
    bool act = n < N;
    float a0 = 0.f, a1 = 0.f, a2 = 0.f, a3 = 0.f, a4 = 0.f;
    if (act) {
        a0 = attrs[n * 5 + 0]; a1 = attrs[n * 5 + 1]; a2 = attrs[n * 5 + 2];
        a3 = attrs[n * 5 + 3]; a4 = attrs[n * 5 + 4];
    }
    float t16[16];
#pragma unroll
    for (int k = 0; k < 16; k++) {
        const float* wr = wv + (c * 16 + k) * 5;   // scalar addr -> s_load
        t16[k] = a0 * wr[0] + a1 * wr[1] + a2 * wr[2] + a3 * wr[3] + a4 * wr[4];
    }
    if (act) {
        float4* hw = (float4*)(h + (size_t)n * 64 + c * 16);
#pragma unroll
        for (int kq = 0; kq < 4; kq++) {
            float4 o; o.x = t16[kq*4]; o.y = t16[kq*4+1]; o.z = t16[kq*4+2]; o.w = t16[kq*4+3];
            hw[kq] = o;
        }
    }
#pragma unroll
    for (int k = 0; k < 16; k++) A[SWZ(node, c * 16 + k)] = t16[k];
    __syncthreads();
    mv16_lds(W, nullptr, c * 16, A, node, t16);
    if (act) {
        union { unsigned int u[8]; _Float16 hh[16]; } pk;
#pragma unroll
        for (int k = 0; k < 16; k++) pk.hh[k] = (_Float16)t16[k];
        unsigned int* o = (unsigned int*)(xfh + (size_t)n * 64 + c * 16);
#pragma unroll
        for (int p = 0; p < 8; p++) o[p] = pk.u[p];
    }
}

// ---------------- fused node update + next lin1: 3 chained matvecs through one LDS tile ----------------
__global__ void __launch_bounds__(256, 4) k_nu_lin1(
    const float* __restrict__ agg,
    const float* __restrict__ lin2w, const float* __restrict__ lin2b,
    const float* __restrict__ linw, const float* __restrict__ linb,
    const float* __restrict__ lin1w_next, int N,
    float* __restrict__ h, _Float16* __restrict__ xfh) {
    __shared__ float A[4096];
    int tid = threadIdx.x;
    int c = __builtin_amdgcn_readfirstlane(tid >> 6);  // SGPR chunk idx -> s_load weights
    int node = tid & 63;
    int n0 = blockIdx.x << 6, n = n0 + node;
    bool act = n < N;
    stage64(agg, A, n0, N, tid);
    __syncthreads();
    float t16[16];
    mv16_lds(lin2w, lin2b, c * 16, A, node, t16);
#pragma unroll
    for (int k = 0; k < 16; k++) t16[k] = sspf(t16[k]);
    __syncthreads();                    // tile fully consumed
#pragma unroll
    for (int k = 0; k < 16; k++) A[SWZ(node, c * 16 + k)] = t16[k];
    __syncthreads();
    mv16_lds(linw, linb, c * 16, A, node, t16);
    if (act) {
        float4* hr = (float4*)(h + (size_t)n * 64 + c * 16);
#pragma unroll
        for (int kq = 0; kq < 4; kq++) {
            float4 hh = hr[kq];
            hh.x += t16[kq * 4 + 0]; hh.y += t16[kq * 4 + 1];
            hh.z += t16[kq * 4 + 2]; hh.w += t16[kq * 4 + 3];
            hr[kq] = hh;
            t16[kq * 4 + 0] = hh.x; t16[kq * 4 + 1] = hh.y;
            t16[kq * 4 + 2] = hh.z; t16[kq * 4 + 3] = hh.w;
        }
    }
    __syncthreads();
#pragma unroll
    for (int k = 0; k < 16; k++) A[SWZ(node, c * 16 + k)] = t16[k];
    __syncthreads();
    mv16_lds(lin1w_next, nullptr, c * 16, A, node, t16);
    if (act) {
        union { unsigned int u[8]; _Float16 hh[16]; } pk;
#pragma unroll
        for (int k = 0; k < 16; k++) pk.hh[k] = (_Float16)t16[k];
        unsigned int* o = (unsigned int*)(xfh + (size_t)n * 64 + c * 16);
#pragma unroll
        for (int p = 0; p < 8; p++) o[p] = pk.u[p];
    }
}

// ---------------- fused layer-1 node update + readout (h never written) ----------------
__global__ void __launch_bounds__(256, 4) k_nu_ro(
    const float* __restrict__ agg,
    const float* __restrict__ lin2w, const float* __restrict__ lin2b,
    const float* __restrict__ linw, const float* __restrict__ linb,
    const float* __restrict__ h,
    const float* __restrict__ ow1, const float* __restrict__ ob1,
    const float* __restrict__ ow2, const float* __restrict__ ob2, int N,
    float* __restrict__ o_node) {
    __shared__ float A[4096];
    int tid = threadIdx.x;
    int c = __builtin_amdgcn_readfirstlane(tid >> 6);  // SGPR chunk idx -> s_load weights
    int node = tid & 63;
    int n0 = blockIdx.x << 6, n = n0 + node;
    bool act = n < N;
    stage64(agg, A, n0, N, tid);
    __syncthreads();
    float t16[16];
    mv16_lds(lin2w, lin2b, c * 16, A, node, t16);
#pragma unroll
    for (int k = 0; k < 16; k++) t16[k] = sspf(t16[k]);
    __syncthreads();
#pragma unroll
    for (int k = 0; k < 16; k++) A[SWZ(node, c * 16 + k)] = t16[k];
    __syncthreads();
    mv16_lds(linw, linb, c * 16, A, node, t16);
    if (act) {
        const float4* hr = (const float4*)(h + (size_t)n * 64 + c * 16);
#pragma unroll
        for (int kq = 0; kq < 4; kq++) {
            float4 hh = hr[kq];
            t16[kq * 4 + 0] += hh.x; t16[kq * 4 + 1] += hh.y;
            t16[kq * 4 + 2] += hh.z; t16[kq * 4 + 3] += hh.w;
        }
    }
    __syncthreads();
#pragma unroll
    for (int k = 0; k < 16; k++) A[SWZ(node, c * 16 + k)] = t16[k];
    __syncthreads();
    // readout: 8 hidden rows per chunk-thread, reading h-row directly from LDS
    float part = 0.f;
    {
        float acc8[8];
#pragma unroll
        for (int k = 0; k < 8; k++) acc8[k] = ob1[c * 8 + k];
#pragma unroll
        for (int j = 0; j < 64; j++) {
            float aj = A[SWZ(node, j)];
#pragma unroll
            for (int k = 0; k < 8; k++) acc8[k] += ow1[(c * 8 + k) * 64 + j] * aj;
        }
#pragma unroll
        for (int k = 0; k < 8; k++) part += sspf(acc8[k]) * ow2[c * 8 + k];
    }
    __syncthreads();                    // tile fully consumed
    A[c * 64 + node] = part;            // linear: lanes=node -> conflict-free
    __syncthreads();
    if (c == 0 && act)
        o_node[n] = A[node] + A[64 + node] + A[128 + node] + A[192 + node] + ob2[0];
}

// ---------------- edge aggregate: wave per node, packed-pair table, 4x unroll ----------------
__global__ void __launch_bounds__(256, 8) k_edge_agg(
    const float4* __restrict__ e_pack, const int* __restrict__ row_start, int N,
    const unsigned int* __restrict__ tab2, const _Float16* __restrict__ xf,
    float* __restrict__ agg) {
    int n = (blockIdx.x * blockDim.x + threadIdx.x) >> 6;
    int lane = threadIdx.x & 63;
    if (n >= N) return;
    int rs = row_start[n], re = row_start[n + 1];
    float acc = 0.f;
    int r = rs;
#define EDGE_TERM(ep) do { \
        int s_ = __float_as_int((ep).x); \
        float x_ = (ep).z * TSCALE; \
        int i0_ = (int)x_; if (i0_ > TBL - 2) i0_ = TBL - 2; \
        float fr_ = fminf(x_ - (float)i0_, 1.0f); \
        union { unsigned int u; _Float16 hh[2]; } cv_; \
        cv_.u = tab2[((size_t)i0_ << 6) + lane]; \
        float t0_ = (float)cv_.hh[0], t1_ = (float)cv_.hh[1]; \
        float xv_ = (float)xf[((size_t)s_ << 6) + lane]; \
        acc += xv_ * (t0_ + (t1_ - t0_) * fr_) * (ep).w; \
    } while (0)
    for (; r + 4 <= re; r += 4) {
        float4 e0 = e_pack[r], e1 = e_pack[r + 1], e2 = e_pack[r + 2], e3 = e_pack[r + 3];
        EDGE_TERM(e0); EDGE_TERM(e1); EDGE_TERM(e2); EDGE_TERM(e3);
    }
    for (; r < re; r++) {
        float4 e0 = e_pack[r];
        EDGE_TERM(e0);
    }
    agg[(size_t)n * 64 + lane] = acc;
#undef EDGE_TERM
}

// ---------------- graph segment boundaries ----------------
__global__ void k_bstart(const int* __restrict__ batch, int N, int G,
                         int* __restrict__ b_start) {
    int g = blockIdx.x * blockDim.x + threadIdx.x;
    if (g > G) return;
    int lo = 0, hi = N;
    while (lo < hi) {
        int mid = (lo + hi) >> 1;
        if (batch[mid] < g) lo = mid + 1;
        else hi = mid;
    }
    b_start[g] = lo;
}

// ---------------- per-graph mean over sorted o_node segments ----------------
__global__ void k_gmean(const float* __restrict__ o_node, const int* __restrict__ b_start,
                        int G, float* __restrict__ out) {
    int g = (blockIdx.x * blockDim.x + threadIdx.x) >> 6;
    int lane = threadIdx.x & 63;
    if (g >= G) return;
    int rs = b_start[g], re = b_start[g + 1];
    float a = 0.f;
    for (int r = rs + lane; r < re; r += 64) a += o_node[r];
#pragma unroll
    for (int m = 1; m < 64; m <<= 1) a += __shfl_xor(a, m, 64);
    if (lane == 0) {
        float cnt = (float)(re - rs);
        out[g] = a / fmaxf(cnt, 1.0f);
    }
}

extern "C" void kernel_launch(void* const* d_in, const int* in_sizes, int n_in,
                              void* d_out, int out_size, void* d_ws, size_t ws_size,
                              hipStream_t stream) {
    const float* pos    = (const float*)d_in[0];
    const float* shifts = (const float*)d_in[1];
    const float* attrs  = (const float*)d_in[2];
    const int*   batch  = (const int*)d_in[3];
    const int*   ei     = (const int*)d_in[4];
    const float* wv     = (const float*)d_in[5];
    const float* mlp_w1 = (const float*)d_in[6];
    const float* mlp_b1 = (const float*)d_in[7];
    const float* mlp_w2 = (const float*)d_in[8];
    const float* mlp_b2 = (const float*)d_in[9];
    const float* lin1w  = (const float*)d_in[10];
    const float* lin2w  = (const float*)d_in[11];
    const float* lin2b  = (const float*)d_in[12];
    const float* linw   = (const float*)d_in[13];
    const float* linb   = (const float*)d_in[14];
    const float* ow1    = (const float*)d_in[15];
    const float* ob1    = (const float*)d_in[16];
    const float* ow2    = (const float*)d_in[17];
    const float* ob2    = (const float*)d_in[18];

    const int N = in_sizes[0] / 3;       // 100000
    const int E = in_sizes[4] / 2;       // 1600000
    const int G = out_size;              // 1000

    char* w = (char*)d_ws;
    size_t off = 0;
    auto alloc = [&](size_t bytes) -> char* {
        char* p = w + off;
        off = (off + bytes + 255) & ~(size_t)255;
        return p;
    };
    int*          cnt       = (int*)alloc((size_t)N * 4);
    int*          row_start = (int*)alloc((size_t)(N + 1) * 4);
    int*          cursor    = (int*)alloc((size_t)N * 4);
    int*          carry     = (int*)alloc(1024 * 4);
    int*          carry_ex  = (int*)alloc(1024 * 4);
    float4*       e_pack    = (float4*)alloc((size_t)E * 16);
    float*        h         = (float*)alloc((size_t)N * HID * 4);
    _Float16*     xfh       = (_Float16*)alloc((size_t)N * FIL * 2);
    float*        agg       = (float*)alloc((size_t)N * FIL * 4);
    _Float16*     tab       = (_Float16*)alloc((size_t)2 * TBL * FIL * 2);
    unsigned int* tab2      = (unsigned int*)alloc((size_t)2 * TBL * FIL * 4);
    float*        o_node    = (float*)alloc((size_t)N * 4);
    int*          b_start   = (int*)alloc((size_t)(G + 1) * 4);
    (void)ws_size;

    const int B = 256;
    const int nblk = (N + 1023) / 1024;
    const int nb64 = (N + 63) / 64;      // 64-node blocks for the LDS-staged kernels

    // CSR build
    hipMemsetAsync(cnt, 0, (size_t)N * 4, stream);
    k_count<<<(E + B - 1) / B, B, 0, stream>>>(ei, E, cnt);
    k_scan_blk<<<nblk, 1024, 0, stream>>>(cnt, N, row_start, carry);
    k_scan_carry<<<1, 1024, 0, stream>>>(carry, nblk, carry_ex);
    k_scan_add<<<(N + B - 1) / B, B, 0, stream>>>(row_start, carry_ex, N, E, cursor);
    k_fill<<<(E + B - 1) / B, B, 0, stream>>>(pos, shifts, ei, E, cursor, e_pack);

    // tables + packing + embed/lin1 + boundaries
    k_table<<<(2 * TBL * 16 + B - 1) / B, B, 0, stream>>>(mlp_w1, mlp_b1, mlp_w2, mlp_b2, tab);
    k_pack<<<(2 * TBL * 64 + B - 1) / B, B, 0, stream>>>(tab, tab2);
    k_embed_lin1<<<nb64, B, 0, stream>>>(attrs, wv, lin1w, N, h, xfh);
    k_bstart<<<(G + 1 + B - 1) / B, B, 0, stream>>>(batch, N, G, b_start);

    const size_t gw = ((size_t)N * 64 + B - 1) / B;
    // layer 0 (node update fused with layer-1 lin1)
    k_edge_agg<<<gw, B, 0, stream>>>(e_pack, row_start, N, tab2, xfh, agg);
    k_nu_lin1<<<nb64, B, 0, stream>>>(agg, lin2w, lin2b, linw, linb,
                                      lin1w + 4096, N, h, xfh);
    // layer 1 (node update fused with readout; h consumed, never rewritten)
    k_edge_agg<<<gw, B, 0, stream>>>(e_pack, row_start, N, tab2 + (size_t)TBL * FIL, xfh, agg);
    k_nu_ro<<<nb64, B, 0, stream>>>(agg, lin2w + 4096, lin2b + 64, linw + 4096, linb + 64,
                                    h, ow1, ob1, ow2, ob2, N, o_node);
    // per-graph mean
    k_gmean<<<((size_t)G * 64 + B - 1) / B, B, 0, stream>>>(o_node, b_start, G, (float*)d_out);
}